// Round 1
// baseline (200.699 us; speedup 1.0000x reference)
//
#include <hip/hip_runtime.h>
#include <hip/hip_bf16.h>

constexpr int Bt    = 131072;
constexpr int OBS   = 194;

// ---- d_ws layout ----
// bytes [0, 57344)        : W1B | WC1B   (layer-1 B-frags, bf16)
// bytes [57344, 92160)    : W2B | WC2B | WHB (layer-2 + head B-frags)
// bytes [98304, 229376)   : evG (1 byte per row)
// bytes [262144, +32 MiB) : hG  (layer-1 output in layer-2 A-frag layout, bf16)
constexpr int W1B_S  = 0;
constexpr int WC1B_S = 14336;
constexpr int W2B_S  = 28672;
constexpr int WC2B_S = 36864;
constexpr int WHB_S  = 45056;
constexpr size_t EVG_B = 98304;     // byte offset of evG
constexpr size_t HG_S  = 131072;    // short offset of hG (byte 262144)

typedef short bf8   __attribute__((ext_vector_type(8)));
typedef float f32x4 __attribute__((ext_vector_type(4)));
typedef unsigned int u32;

__device__ __forceinline__ short f2bs(float f) {
    union { __hip_bfloat16 h; short s; } u;
    u.h = __float2bfloat16(f);
    return u.s;
}
__device__ __forceinline__ float bs2f(short s) {
    union { short s; __hip_bfloat16 h; } u;
    u.s = s;
    return __bfloat162float(u.h);
}
__device__ __forceinline__ u32 pk2(float a, float b) {
    union { __hip_bfloat162 h; u32 u; } r;
    r.h = __float22bfloat162_rn(float2{a, b});
    return r.u;
}
__device__ __forceinline__ float fast_tanh(float v) {
    v = fminf(fmaxf(v, -15.f), 15.f);
    float e = __expf(2.f * v);
    return (e - 1.f) * __builtin_amdgcn_rcpf(e + 1.f);
}
__device__ __forceinline__ void dma16(const void* g, void* s) {
    __builtin_amdgcn_global_load_lds(
        (const __attribute__((address_space(1))) u32*)g,
        (__attribute__((address_space(3))) u32*)s, 16, 0, 0);
}

// ---------------- prep: weights -> B-fragment layout in d_ws (unchanged) ----------------
__global__ void __launch_bounds__(256) prep(
    const float* __restrict__ W1, const float* __restrict__ b1,
    const float* __restrict__ W2, const float* __restrict__ Wh,
    const float* __restrict__ Wc1, const float* __restrict__ bc1,
    const float* __restrict__ Wc2, const float* __restrict__ Wc3,
    short* __restrict__ ws)
{
    const int gid = blockIdx.x * 256 + threadIdx.x;
    const int gsz = gridDim.x * 256;

    for (int i = gid; i < 14336; i += gsz) {
        int j = i & 7, l = (i >> 3) & 63, nt = (i >> 9) & 3, kb = i >> 11;
        int k = kb * 32 + ((l >> 4) << 3) + j;
        int n = nt * 16 + (l & 15);
        short v1 = 0, v2 = 0;
        if (k < OBS) {
            v1 = f2bs(W1[k * 64 + n]);
            v2 = f2bs(Wc1[k * 64 + n]);
        } else if (k == OBS) {              // bias row (A supplies 1.0)
            v1 = f2bs(b1[n]);
            v2 = f2bs(bc1[n]);
        }
        ws[W1B_S + i]  = v1;
        ws[WC1B_S + i] = v2;
    }
    for (int i = gid; i < 8192; i += gsz) {
        int j = i & 7, l = (i >> 3) & 63, nt = (i >> 9) & 3, kb = i >> 11;
        int s = kb * 32 + ((l >> 4) << 3) + j;
        int kp = (s & 3) * 16 + (s >> 2);   // gamma(s)
        int n = nt * 16 + (l & 15);
        ws[W2B_S + i]  = f2bs(W2[kp * 64 + n]);
        ws[WC2B_S + i] = f2bs(Wc2[kp * 64 + n]);
    }
    for (int i = gid; i < 1024; i += gsz) {
        int j = i & 7, l = (i >> 3) & 63, kb = i >> 9;
        int s = kb * 32 + ((l >> 4) << 3) + j;
        int kp = (s & 3) * 16 + (s >> 2);
        int cc = l & 15;
        float v;
        if (cc == 15) v = Wc3[kp];
        else { int e = cc / 5, a = cc - 5 * e; v = Wh[(e * 64 + kp) * 5 + a]; }
        ws[WHB_S + i] = f2bs(v);
    }
}

// ---------------- trunk1: layer 1 (actor+critic) + ev, linear-DMA x ingest ----------------
constexpr int P1_XS0 = 57344;            // per-wave x-stage base
constexpr int P1_XSS = 12544;            // per-wave x-stage stride (12416 + pad)
constexpr int P1_LDS = P1_XS0 + 8 * P1_XSS;  // 157696 B

__global__ void __launch_bounds__(512, 2) trunk1(
    const float* __restrict__ x, const short* __restrict__ ws,
    short* __restrict__ hG, unsigned char* __restrict__ evG)
{
    __shared__ __align__(16) char smem[P1_LDS];
    const int t = threadIdx.x;
    const int w = t >> 6, l = t & 63, q = l >> 4, c = l & 15;

    // weights -> LDS: 57344 B = 3584 x 16-B chunks, 512 threads -> 7 iters exact
    #pragma unroll
    for (int i = 0; i < 7; ++i) {
        int idx = i * 512 + t;
        dma16((const char*)ws + idx * 16, smem + idx * 16);
    }

    char* xs = smem + P1_XS0 + w * P1_XSS;
    const int t0 = blockIdx.x * 32 + w * 4;          // first tile of this wave

    { // first tile: linear copy of 12416 B (16 rows x 776 B)
        const char* src = (const char*)x + (size_t)t0 * 12416;
        #pragma unroll
        for (int ch = 0; ch < 12; ++ch)
            dma16(src + ch * 1024 + l * 16, xs + ch * 1024 + l * 16);
        if (l < 8) {
            int4 v = *reinterpret_cast<const int4*>(src + 12288 + l * 16);
            *reinterpret_cast<int4*>(xs + 12288 + l * 16) = v;
        }
    }

    __syncthreads();   // weights + first x tile resident (drains vmcnt)

    const bf8* fW1L  = reinterpret_cast<const bf8*>(smem);
    const bf8* fWc1L = reinterpret_cast<const bf8*>(smem + 28672);
    // ha/hc bounce scratch reuses the x-stage (x is dead after pack)
    short* ha = reinterpret_cast<short*>(xs);
    short* hc = ha + 1152;

    #pragma unroll 1
    for (int i = 0; i < 4; ++i) {
        const int tt = t0 + i;

        // ensure this tile's DMA landed (prev iter's stores drain too; they're old)
        asm volatile("s_waitcnt vmcnt(0)" ::: "memory");
        __builtin_amdgcn_sched_barrier(0);

        // ---- pack A-frags from LDS (identical values to old loadraw/packaf) ----
        union AF { u32 u[4]; bf8 v; } af[7];
        #pragma unroll
        for (int kb = 0; kb < 6; ++kb) {
            #pragma unroll
            for (int j = 0; j < 4; ++j) {
                float2 v = *reinterpret_cast<const float2*>(xs + c * 776 + kb * 128 + q * 32 + j * 8);
                af[kb].u[j] = pk2(v.x, v.y);
            }
        }
        af[6].u[0] = 0; af[6].u[1] = 0; af[6].u[2] = 0; af[6].u[3] = 0;
        if (q == 0) {                       // k=192,193 data; k=194 -> 1.0 (bias row)
            float2 v = *reinterpret_cast<const float2*>(xs + c * 776 + 768);
            af[6].u[0] = pk2(v.x, v.y);
            af[6].u[1] = pk2(1.0f, 0.0f);
        }
        // ---- ev (argmax of x[0..2], f32) for rows 0-15; store to ws ----
        if (l < 16) {
            float2 v01 = *reinterpret_cast<const float2*>(xs + l * 776);
            float  v2  = *reinterpret_cast<const float*>(xs + l * 776 + 8);
            int ev = 0; float b = v01.x;
            if (v01.y > b) { b = v01.y; ev = 1; }
            if (v2 > b) ev = 2;
            evG[tt * 16 + l] = (unsigned char)ev;
        }

        // ---- layer 1: actor + critic (bias folded via k=194 row) ----
        f32x4 aa[4], ac[4];
        #pragma unroll
        for (int nt = 0; nt < 4; ++nt) {
            aa[nt] = f32x4{0.f, 0.f, 0.f, 0.f};
            ac[nt] = f32x4{0.f, 0.f, 0.f, 0.f};
        }
        #pragma unroll
        for (int kb = 0; kb < 7; ++kb) {
            bf8 a = af[kb].v;
            #pragma unroll
            for (int nt = 0; nt < 4; ++nt) {
                aa[nt] = __builtin_amdgcn_mfma_f32_16x16x32_bf16(a, fW1L [(kb * 4 + nt) * 64 + l], aa[nt], 0, 0, 0);
                ac[nt] = __builtin_amdgcn_mfma_f32_16x16x32_bf16(a, fWc1L[(kb * 4 + nt) * 64 + l], ac[nt], 0, 0, 0);
            }
        }
        // ---- tanh -> packed wave-local bounce (slot 4c+nt = col nt*16+c; gamma on B side) ----
        #pragma unroll
        for (int r = 0; r < 4; ++r) {
            uint2 pa, pc;
            pa.x = pk2(fast_tanh(aa[0][r]), fast_tanh(aa[1][r]));
            pa.y = pk2(fast_tanh(aa[2][r]), fast_tanh(aa[3][r]));
            pc.x = pk2(fast_tanh(ac[0][r]), fast_tanh(ac[1][r]));
            pc.y = pk2(fast_tanh(ac[2][r]), fast_tanh(ac[3][r]));
            *reinterpret_cast<uint2*>(&ha[(q * 4 + r) * 72 + 4 * c]) = pa;
            *reinterpret_cast<uint2*>(&hc[(q * 4 + r) * 72 + 4 * c]) = pc;
        }
        // ---- read layer-2 A-frags and store to global (coalesced dwordx4) ----
        #pragma unroll
        for (int kb = 0; kb < 2; ++kb) {
            bf8 va = *reinterpret_cast<const bf8*>(&ha[c * 72 + kb * 32 + q * 8]);
            bf8 vc = *reinterpret_cast<const bf8*>(&hc[c * 72 + kb * 32 + q * 8]);
            *reinterpret_cast<bf8*>(hG + ((size_t)(tt * 4 + kb)     * 64 + l) * 8) = va;
            *reinterpret_cast<bf8*>(hG + ((size_t)(tt * 4 + 2 + kb) * 64 + l) * 8) = vc;
        }

        // ---- prefetch next tile (issued after frag reads have been consumed) ----
        if (i < 3) {
            const char* src = (const char*)x + (size_t)(tt + 1) * 12416;
            #pragma unroll
            for (int ch = 0; ch < 12; ++ch)
                dma16(src + ch * 1024 + l * 16, xs + ch * 1024 + l * 16);
            if (l < 8) {
                int4 v = *reinterpret_cast<const int4*>(src + 12288 + l * 16);
                *reinterpret_cast<int4*>(xs + 12288 + l * 16) = v;
            }
        }
    }
}

// ---------------- head2: layer 2 + head + epilogue (2 blocks/CU) ----------------
constexpr int F2_W   = 34816;            // W2B|WC2B|WHB in LDS
constexpr int F2_PW  = 5248;             // per-wave: ha 2304 | hc 2304 | lw 576 | vb 64
constexpr int F2_LDS = F2_W + 8 * F2_PW; // 76800 B -> 2 blocks/CU

__global__ void __launch_bounds__(512, 4) head2(
    const int* __restrict__ act_in,
    const float* __restrict__ b2, const float* __restrict__ bc2,
    const float* __restrict__ bh, const float* __restrict__ bc3,
    const short* __restrict__ ws,
    const short* __restrict__ hG, const unsigned char* __restrict__ evG,
    float* __restrict__ out)
{
    __shared__ __align__(16) char smem[F2_LDS];
    const int t = threadIdx.x;
    const int w = t >> 6, l = t & 63, q = l >> 4, c = l & 15;

    // weights -> LDS: 34816 B = 2176 chunks (wave-uniform mask at i=4)
    #pragma unroll
    for (int i = 0; i < 5; ++i) {
        int idx = i * 512 + t;
        if (idx < 2176)
            dma16((const char*)ws + 57344 + idx * 16, smem + idx * 16);
    }

    float b2v[4], bc2v[4];
    #pragma unroll
    for (int nt = 0; nt < 4; ++nt) {
        b2v[nt]  = b2[nt * 16 + c];
        bc2v[nt] = bc2[nt * 16 + c];
    }
    float bhv = (c < 15) ? bh[c] : bc3[0];

    __syncthreads();

    const bf8* fW2L  = reinterpret_cast<const bf8*>(smem);
    const bf8* fWc2L = reinterpret_cast<const bf8*>(smem + 16384);
    const bf8* fWhL  = reinterpret_cast<const bf8*>(smem + 32768);
    short* ha = reinterpret_cast<short*>(smem + F2_W + w * F2_PW);
    short* hc = ha + 1152;
    short* lw = reinterpret_cast<short*>(smem + F2_W + w * F2_PW + 4608);
    float* vb = reinterpret_cast<float*>(smem + F2_W + w * F2_PW + 5184);

    #pragma unroll 1
    for (int i = 0; i < 2; ++i) {
        const int tt = blockIdx.x * 16 + w * 2 + i;
        const int gm = tt * 16 + c;
        int act = 0, evc = 0;
        if (l < 16) { act = act_in[gm]; evc = evG[gm]; }

        // layer-2 A-frags: 4 coalesced dwordx4 per lane
        bf8 xa[2], xc[2];
        #pragma unroll
        for (int kb = 0; kb < 2; ++kb) {
            xa[kb] = *reinterpret_cast<const bf8*>(hG + ((size_t)(tt * 4 + kb)     * 64 + l) * 8);
            xc[kb] = *reinterpret_cast<const bf8*>(hG + ((size_t)(tt * 4 + 2 + kb) * 64 + l) * 8);
        }

        // ---- layer 2 (bias via acc init) ----
        f32x4 aa[4], ac[4];
        #pragma unroll
        for (int nt = 0; nt < 4; ++nt) {
            aa[nt] = f32x4{b2v[nt], b2v[nt], b2v[nt], b2v[nt]};
            ac[nt] = f32x4{bc2v[nt], bc2v[nt], bc2v[nt], bc2v[nt]};
        }
        #pragma unroll
        for (int kb = 0; kb < 2; ++kb) {
            #pragma unroll
            for (int nt = 0; nt < 4; ++nt) {
                aa[nt] = __builtin_amdgcn_mfma_f32_16x16x32_bf16(xa[kb], fW2L [(kb * 4 + nt) * 64 + l], aa[nt], 0, 0, 0);
                ac[nt] = __builtin_amdgcn_mfma_f32_16x16x32_bf16(xc[kb], fWc2L[(kb * 4 + nt) * 64 + l], ac[nt], 0, 0, 0);
            }
        }
        #pragma unroll
        for (int r = 0; r < 4; ++r) {
            uint2 pa, pc;
            pa.x = pk2(fast_tanh(aa[0][r]), fast_tanh(aa[1][r]));
            pa.y = pk2(fast_tanh(aa[2][r]), fast_tanh(aa[3][r]));
            pc.x = pk2(fast_tanh(ac[0][r]), fast_tanh(ac[1][r]));
            pc.y = pk2(fast_tanh(ac[2][r]), fast_tanh(ac[3][r]));
            *reinterpret_cast<uint2*>(&ha[(q * 4 + r) * 72 + 4 * c]) = pa;
            *reinterpret_cast<uint2*>(&hc[(q * 4 + r) * 72 + 4 * c]) = pc;
        }

        // ---- head: feat[16x64] @ [64x16] (cols 0-14 logits, col 15 value) ----
        {
            f32x4 lg = f32x4{bhv, bhv, bhv, bhv};
            f32x4 vv = f32x4{bhv, bhv, bhv, bhv};
            #pragma unroll
            for (int kb = 0; kb < 2; ++kb) {
                bf8 bw = fWhL[kb * 64 + l];
                bf8 fa = *reinterpret_cast<const bf8*>(&ha[c * 72 + kb * 32 + q * 8]);
                bf8 fc = *reinterpret_cast<const bf8*>(&hc[c * 72 + kb * 32 + q * 8]);
                lg = __builtin_amdgcn_mfma_f32_16x16x32_bf16(fa, bw, lg, 0, 0, 0);
                vv = __builtin_amdgcn_mfma_f32_16x16x32_bf16(fc, bw, vv, 0, 0, 0);
            }
            #pragma unroll
            for (int r = 0; r < 4; ++r)
                lw[(q * 4 + r) * 18 + c] = f2bs(lg[r]);
            if (c == 15) {
                #pragma unroll
                for (int r = 0; r < 4; ++r)
                    vb[q * 4 + r] = vv[r];
            }
        }

        // ---- epilogue: lanes 0-15 (wave-local LDS, in-order DS pipe) ----
        if (l < 16) {
            float lg[5];
            #pragma unroll
            for (int a = 0; a < 5; ++a)
                lg[a] = bs2f(lw[c * 18 + evc * 5 + a]);
            float mx = lg[0];
            #pragma unroll
            for (int a = 1; a < 5; ++a) mx = fmaxf(mx, lg[a]);
            float se = 0.f;
            #pragma unroll
            for (int a = 0; a < 5; ++a) se += __expf(lg[a] - mx);
            float lse = __logf(se) + mx;
            float lsel = lg[0];
            #pragma unroll
            for (int a = 1; a < 5; ++a) lsel = (act == a) ? lg[a] : lsel;
            float ent = 0.f;
            #pragma unroll
            for (int a = 0; a < 5; ++a) { float lp = lg[a] - lse; ent -= __expf(lp) * lp; }

            out[gm]          = (float)act;
            out[Bt + gm]     = lsel - lse;
            out[2 * Bt + gm] = ent;
            out[3 * Bt + gm] = vb[c];
        }
    }
}

extern "C" void kernel_launch(void* const* d_in, const int* in_sizes, int n_in,
                              void* d_out, int out_size, void* d_ws, size_t ws_size,
                              hipStream_t stream) {
    const float* x   = (const float*)d_in[0];
    const int*   act = (const int*)  d_in[1];
    const float* W1  = (const float*)d_in[2];
    const float* b1  = (const float*)d_in[3];
    const float* W2  = (const float*)d_in[4];
    const float* b2  = (const float*)d_in[5];
    const float* Wh  = (const float*)d_in[6];
    const float* bh  = (const float*)d_in[7];
    const float* Wc1 = (const float*)d_in[8];
    const float* bc1 = (const float*)d_in[9];
    const float* Wc2 = (const float*)d_in[10];
    const float* bc2 = (const float*)d_in[11];
    const float* Wc3 = (const float*)d_in[12];
    const float* bc3 = (const float*)d_in[13];
    float* out = (float*)d_out;
    short* ws  = (short*)d_ws;
    short* hG  = ws + HG_S;
    unsigned char* evG = (unsigned char*)d_ws + EVG_B;

    hipLaunchKernelGGL(prep, dim3(32), dim3(256), 0, stream,
                       W1, b1, W2, Wh, Wc1, bc1, Wc2, Wc3, ws);
    hipLaunchKernelGGL(trunk1, dim3(256), dim3(512), 0, stream,
                       x, ws, hG, evG);
    hipLaunchKernelGGL(head2, dim3(512), dim3(512), 0, stream,
                       act, b2, bc2, bh, bc3, ws, hG, evG, out);
}

// Round 2
// 197.810 us; speedup vs baseline: 1.0146x; 1.0146x over previous
//
#include <hip/hip_runtime.h>
#include <hip/hip_bf16.h>

constexpr int Bt    = 131072;
constexpr int OBS   = 194;

// ---- d_ws layout ----
// bytes [0, 57344)        : W1B | WC1B   (layer-1 B-frags, bf16)
// bytes [57344, 92160)    : W2B | WC2B | WHB (layer-2 + head B-frags)
// bytes [98304, 229376)   : evG (1 byte per row)
// bytes [262144, +32 MiB) : hG  (layer-1 output, packed-C layout [tile][2][16][64] bf16)
constexpr int W1B_S  = 0;
constexpr int WC1B_S = 14336;
constexpr int W2B_S  = 28672;
constexpr int WC2B_S = 36864;
constexpr int WHB_S  = 45056;
constexpr size_t EVG_B = 98304;     // byte offset of evG
constexpr size_t HG_S  = 131072;    // short offset of hG (byte 262144)

typedef short bf8   __attribute__((ext_vector_type(8)));
typedef float f32x4 __attribute__((ext_vector_type(4)));
typedef unsigned int u32;

__device__ __forceinline__ short f2bs(float f) {
    union { __hip_bfloat16 h; short s; } u;
    u.h = __float2bfloat16(f);
    return u.s;
}
__device__ __forceinline__ float bs2f(short s) {
    union { short s; __hip_bfloat16 h; } u;
    u.s = s;
    return __bfloat162float(u.h);
}
__device__ __forceinline__ u32 pk2(float a, float b) {
    union { __hip_bfloat162 h; u32 u; } r;
    r.h = __float22bfloat162_rn(float2{a, b});
    return r.u;
}
__device__ __forceinline__ float fast_tanh(float v) {
    v = fminf(fmaxf(v, -15.f), 15.f);
    float e = __expf(2.f * v);
    return (e - 1.f) * __builtin_amdgcn_rcpf(e + 1.f);
}
__device__ __forceinline__ void dma16(const void* g, void* s) {
    __builtin_amdgcn_global_load_lds(
        (const __attribute__((address_space(1))) u32*)g,
        (__attribute__((address_space(3))) u32*)s, 16, 0, 0);
}

// ---------------- prep: weights -> B-fragment layout in d_ws (unchanged) ----------------
__global__ void __launch_bounds__(256) prep(
    const float* __restrict__ W1, const float* __restrict__ b1,
    const float* __restrict__ W2, const float* __restrict__ Wh,
    const float* __restrict__ Wc1, const float* __restrict__ bc1,
    const float* __restrict__ Wc2, const float* __restrict__ Wc3,
    short* __restrict__ ws)
{
    const int gid = blockIdx.x * 256 + threadIdx.x;
    const int gsz = gridDim.x * 256;

    for (int i = gid; i < 14336; i += gsz) {
        int j = i & 7, l = (i >> 3) & 63, nt = (i >> 9) & 3, kb = i >> 11;
        int k = kb * 32 + ((l >> 4) << 3) + j;
        int n = nt * 16 + (l & 15);
        short v1 = 0, v2 = 0;
        if (k < OBS) {
            v1 = f2bs(W1[k * 64 + n]);
            v2 = f2bs(Wc1[k * 64 + n]);
        } else if (k == OBS) {              // bias row (A supplies 1.0)
            v1 = f2bs(b1[n]);
            v2 = f2bs(bc1[n]);
        }
        ws[W1B_S + i]  = v1;
        ws[WC1B_S + i] = v2;
    }
    for (int i = gid; i < 8192; i += gsz) {
        int j = i & 7, l = (i >> 3) & 63, nt = (i >> 9) & 3, kb = i >> 11;
        int s = kb * 32 + ((l >> 4) << 3) + j;
        int kp = (s & 3) * 16 + (s >> 2);   // gamma(s)
        int n = nt * 16 + (l & 15);
        ws[W2B_S + i]  = f2bs(W2[kp * 64 + n]);
        ws[WC2B_S + i] = f2bs(Wc2[kp * 64 + n]);
    }
    for (int i = gid; i < 1024; i += gsz) {
        int j = i & 7, l = (i >> 3) & 63, kb = i >> 9;
        int s = kb * 32 + ((l >> 4) << 3) + j;
        int kp = (s & 3) * 16 + (s >> 2);
        int cc = l & 15;
        float v;
        if (cc == 15) v = Wc3[kp];
        else { int e = cc / 5, a = cc - 5 * e; v = Wh[(e * 64 + kp) * 5 + a]; }
        ws[WHB_S + i] = f2bs(v);
    }
}

// ---------------- trunk1: layer 1 (actor+critic) + ev ----------------
// Schedule per iteration: wait(tile i) -> pack to regs + ev -> ISSUE DMA(tile i+1,
// same buffer; xs is dead after pack) -> MFMA + tanh + global stores (overlap DMA).
constexpr int P1_XS0 = 57344;            // per-wave x-stage base
constexpr int P1_XSS = 12544;            // per-wave x-stage stride (12416 + pad)
constexpr int P1_LDS = P1_XS0 + 8 * P1_XSS;  // 157696 B

__global__ void __launch_bounds__(512, 2) trunk1(
    const float* __restrict__ x, const short* __restrict__ ws,
    short* __restrict__ hG, unsigned char* __restrict__ evG)
{
    __shared__ __align__(16) char smem[P1_LDS];
    const int t = threadIdx.x;
    const int w = t >> 6, l = t & 63, q = l >> 4, c = l & 15;

    // weights -> LDS: 57344 B = 3584 x 16-B chunks, 512 threads -> 7 iters exact
    #pragma unroll
    for (int i = 0; i < 7; ++i) {
        int idx = i * 512 + t;
        dma16((const char*)ws + idx * 16, smem + idx * 16);
    }

    char* xs = smem + P1_XS0 + w * P1_XSS;
    const int t0 = blockIdx.x * 32 + w * 4;          // first tile of this wave

    // linear stage of one 16-row tile (12416 B): 12 chunks + overlapped tail chunk
    auto stage = [&](int tt) {
        const char* src = (const char*)x + (size_t)tt * 12416;
        #pragma unroll
        for (int ch = 0; ch < 12; ++ch)
            dma16(src + ch * 1024 + l * 16, xs + ch * 1024 + l * 16);
        dma16(src + 11392 + l * 16, xs + 11392 + l * 16);   // bytes [11392,12416)
    };
    stage(t0);

    __syncthreads();   // weights + first x tile resident (drains vmcnt)

    const bf8* fW1L  = reinterpret_cast<const bf8*>(smem);
    const bf8* fWc1L = reinterpret_cast<const bf8*>(smem + 28672);

    #pragma unroll 1
    for (int i = 0; i < 4; ++i) {
        const int tt = t0 + i;

        if (i) {   // tile i's DMA was issued mid-iteration i-1; wait for it here
            asm volatile("s_waitcnt vmcnt(0)" ::: "memory");
            __builtin_amdgcn_sched_barrier(0);
        }

        // ---- pack A-frags from LDS into registers (xs dead afterwards) ----
        union AF { u32 u[4]; bf8 v; } af[7];
        #pragma unroll
        for (int kb = 0; kb < 6; ++kb) {
            #pragma unroll
            for (int j = 0; j < 4; ++j) {
                float2 v = *reinterpret_cast<const float2*>(xs + c * 776 + kb * 128 + q * 32 + j * 8);
                af[kb].u[j] = pk2(v.x, v.y);
            }
        }
        af[6].u[0] = 0; af[6].u[1] = 0; af[6].u[2] = 0; af[6].u[3] = 0;
        if (q == 0) {                       // k=192,193 data; k=194 -> 1.0 (bias row)
            float2 v = *reinterpret_cast<const float2*>(xs + c * 776 + 768);
            af[6].u[0] = pk2(v.x, v.y);
            af[6].u[1] = pk2(1.0f, 0.0f);
        }
        // ---- ev (argmax of x[0..2], f32) for rows 0-15 ----
        if (l < 16) {
            float2 v01 = *reinterpret_cast<const float2*>(xs + l * 776);
            float  v2  = *reinterpret_cast<const float*>(xs + l * 776 + 8);
            int ev = 0; float b = v01.x;
            if (v01.y > b) { b = v01.y; ev = 1; }
            if (v2 > b) ev = 2;
            evG[tt * 16 + l] = (unsigned char)ev;
        }

        // ---- issue next tile's DMA NOW (into same xs; overlaps the compute below) ----
        __builtin_amdgcn_sched_barrier(0);      // keep xs reads above the DMA issue
        if (i < 3) stage(tt + 1);
        __builtin_amdgcn_sched_barrier(0);

        // ---- layer 1: actor + critic (bias folded via k=194 row) ----
        f32x4 aa[4], ac[4];
        #pragma unroll
        for (int nt = 0; nt < 4; ++nt) {
            aa[nt] = f32x4{0.f, 0.f, 0.f, 0.f};
            ac[nt] = f32x4{0.f, 0.f, 0.f, 0.f};
        }
        #pragma unroll
        for (int kb = 0; kb < 7; ++kb) {
            bf8 a = af[kb].v;
            #pragma unroll
            for (int nt = 0; nt < 4; ++nt) {
                aa[nt] = __builtin_amdgcn_mfma_f32_16x16x32_bf16(a, fW1L [(kb * 4 + nt) * 64 + l], aa[nt], 0, 0, 0);
                ac[nt] = __builtin_amdgcn_mfma_f32_16x16x32_bf16(a, fWc1L[(kb * 4 + nt) * 64 + l], ac[nt], 0, 0, 0);
            }
        }
        // ---- tanh -> packed-C layout straight to global (no LDS bounce) ----
        // slot 4c+nt = col nt*16+c of row q*4+r; gamma is baked into W2/Wc2 B-frags.
        short* hGt = hG + (size_t)tt * 2048;
        #pragma unroll
        for (int r = 0; r < 4; ++r) {
            uint2 pa, pc;
            pa.x = pk2(fast_tanh(aa[0][r]), fast_tanh(aa[1][r]));
            pa.y = pk2(fast_tanh(aa[2][r]), fast_tanh(aa[3][r]));
            pc.x = pk2(fast_tanh(ac[0][r]), fast_tanh(ac[1][r]));
            pc.y = pk2(fast_tanh(ac[2][r]), fast_tanh(ac[3][r]));
            *reinterpret_cast<uint2*>(hGt + (q * 4 + r) * 64 + 4 * c)        = pa;
            *reinterpret_cast<uint2*>(hGt + 1024 + (q * 4 + r) * 64 + 4 * c) = pc;
        }
    }
}

// ---------------- head2: layer 2 + head + epilogue (2 blocks/CU) ----------------
constexpr int F2_W   = 34816;            // W2B|WC2B|WHB in LDS
constexpr int F2_PW  = 5248;             // per-wave: ha 2304 | hc 2304 | lw 576 | vb 64
constexpr int F2_LDS = F2_W + 8 * F2_PW; // 76800 B -> 2 blocks/CU

__global__ void __launch_bounds__(512, 4) head2(
    const int* __restrict__ act_in,
    const float* __restrict__ b2, const float* __restrict__ bc2,
    const float* __restrict__ bh, const float* __restrict__ bc3,
    const short* __restrict__ ws,
    const short* __restrict__ hG, const unsigned char* __restrict__ evG,
    float* __restrict__ out)
{
    __shared__ __align__(16) char smem[F2_LDS];
    const int t = threadIdx.x;
    const int w = t >> 6, l = t & 63, q = l >> 4, c = l & 15;

    // weights -> LDS: 34816 B = 2176 chunks (wave-uniform mask at i=4)
    #pragma unroll
    for (int i = 0; i < 5; ++i) {
        int idx = i * 512 + t;
        if (idx < 2176)
            dma16((const char*)ws + 57344 + idx * 16, smem + idx * 16);
    }

    float b2v[4], bc2v[4];
    #pragma unroll
    for (int nt = 0; nt < 4; ++nt) {
        b2v[nt]  = b2[nt * 16 + c];
        bc2v[nt] = bc2[nt * 16 + c];
    }
    float bhv = (c < 15) ? bh[c] : bc3[0];

    __syncthreads();

    const bf8* fW2L  = reinterpret_cast<const bf8*>(smem);
    const bf8* fWc2L = reinterpret_cast<const bf8*>(smem + 16384);
    const bf8* fWhL  = reinterpret_cast<const bf8*>(smem + 32768);
    short* ha = reinterpret_cast<short*>(smem + F2_W + w * F2_PW);
    short* hc = ha + 1152;
    short* lw = reinterpret_cast<short*>(smem + F2_W + w * F2_PW + 4608);
    float* vb = reinterpret_cast<float*>(smem + F2_W + w * F2_PW + 5184);

    #pragma unroll 1
    for (int i = 0; i < 2; ++i) {
        const int tt = blockIdx.x * 16 + w * 2 + i;
        const int gm = tt * 16 + c;
        int act = 0, evc = 0;
        if (l < 16) { act = act_in[gm]; evc = evG[gm]; }

        // ---- load packed-C h tile (coalesced uint2) and bounce through LDS ----
        const short* hGt = hG + (size_t)tt * 2048;
        uint2 va[4], vc2[4];
        #pragma unroll
        for (int r = 0; r < 4; ++r) {
            va[r]  = *reinterpret_cast<const uint2*>(hGt + (q * 4 + r) * 64 + 4 * c);
            vc2[r] = *reinterpret_cast<const uint2*>(hGt + 1024 + (q * 4 + r) * 64 + 4 * c);
        }
        #pragma unroll
        for (int r = 0; r < 4; ++r) {
            *reinterpret_cast<uint2*>(&ha[(q * 4 + r) * 72 + 4 * c]) = va[r];
            *reinterpret_cast<uint2*>(&hc[(q * 4 + r) * 72 + 4 * c]) = vc2[r];
        }
        // layer-2 A-frags (wave-local transpose read)
        bf8 xa[2], xc[2];
        #pragma unroll
        for (int kb = 0; kb < 2; ++kb) {
            xa[kb] = *reinterpret_cast<const bf8*>(&ha[c * 72 + kb * 32 + q * 8]);
            xc[kb] = *reinterpret_cast<const bf8*>(&hc[c * 72 + kb * 32 + q * 8]);
        }

        // ---- layer 2 (bias via acc init) ----
        f32x4 aa[4], ac[4];
        #pragma unroll
        for (int nt = 0; nt < 4; ++nt) {
            aa[nt] = f32x4{b2v[nt], b2v[nt], b2v[nt], b2v[nt]};
            ac[nt] = f32x4{bc2v[nt], bc2v[nt], bc2v[nt], bc2v[nt]};
        }
        #pragma unroll
        for (int kb = 0; kb < 2; ++kb) {
            #pragma unroll
            for (int nt = 0; nt < 4; ++nt) {
                aa[nt] = __builtin_amdgcn_mfma_f32_16x16x32_bf16(xa[kb], fW2L [(kb * 4 + nt) * 64 + l], aa[nt], 0, 0, 0);
                ac[nt] = __builtin_amdgcn_mfma_f32_16x16x32_bf16(xc[kb], fWc2L[(kb * 4 + nt) * 64 + l], ac[nt], 0, 0, 0);
            }
        }
        #pragma unroll
        for (int r = 0; r < 4; ++r) {
            uint2 pa, pc;
            pa.x = pk2(fast_tanh(aa[0][r]), fast_tanh(aa[1][r]));
            pa.y = pk2(fast_tanh(aa[2][r]), fast_tanh(aa[3][r]));
            pc.x = pk2(fast_tanh(ac[0][r]), fast_tanh(ac[1][r]));
            pc.y = pk2(fast_tanh(ac[2][r]), fast_tanh(ac[3][r]));
            *reinterpret_cast<uint2*>(&ha[(q * 4 + r) * 72 + 4 * c]) = pa;
            *reinterpret_cast<uint2*>(&hc[(q * 4 + r) * 72 + 4 * c]) = pc;
        }

        // ---- head: feat[16x64] @ [64x16] (cols 0-14 logits, col 15 value) ----
        {
            f32x4 lg = f32x4{bhv, bhv, bhv, bhv};
            f32x4 vv = f32x4{bhv, bhv, bhv, bhv};
            #pragma unroll
            for (int kb = 0; kb < 2; ++kb) {
                bf8 bw = fWhL[kb * 64 + l];
                bf8 fa = *reinterpret_cast<const bf8*>(&ha[c * 72 + kb * 32 + q * 8]);
                bf8 fc = *reinterpret_cast<const bf8*>(&hc[c * 72 + kb * 32 + q * 8]);
                lg = __builtin_amdgcn_mfma_f32_16x16x32_bf16(fa, bw, lg, 0, 0, 0);
                vv = __builtin_amdgcn_mfma_f32_16x16x32_bf16(fc, bw, vv, 0, 0, 0);
            }
            #pragma unroll
            for (int r = 0; r < 4; ++r)
                lw[(q * 4 + r) * 18 + c] = f2bs(lg[r]);
            if (c == 15) {
                #pragma unroll
                for (int r = 0; r < 4; ++r)
                    vb[q * 4 + r] = vv[r];
            }
        }

        // ---- epilogue: lanes 0-15 (wave-local LDS, in-order DS pipe) ----
        if (l < 16) {
            float lg[5];
            #pragma unroll
            for (int a = 0; a < 5; ++a)
                lg[a] = bs2f(lw[c * 18 + evc * 5 + a]);
            float mx = lg[0];
            #pragma unroll
            for (int a = 1; a < 5; ++a) mx = fmaxf(mx, lg[a]);
            float se = 0.f;
            #pragma unroll
            for (int a = 0; a < 5; ++a) se += __expf(lg[a] - mx);
            float lse = __logf(se) + mx;
            float lsel = lg[0];
            #pragma unroll
            for (int a = 1; a < 5; ++a) lsel = (act == a) ? lg[a] : lsel;
            float ent = 0.f;
            #pragma unroll
            for (int a = 0; a < 5; ++a) { float lp = lg[a] - lse; ent -= __expf(lp) * lp; }

            out[gm]          = (float)act;
            out[Bt + gm]     = lsel - lse;
            out[2 * Bt + gm] = ent;
            out[3 * Bt + gm] = vb[c];
        }
    }
}

extern "C" void kernel_launch(void* const* d_in, const int* in_sizes, int n_in,
                              void* d_out, int out_size, void* d_ws, size_t ws_size,
                              hipStream_t stream) {
    const float* x   = (const float*)d_in[0];
    const int*   act = (const int*)  d_in[1];
    const float* W1  = (const float*)d_in[2];
    const float* b1  = (const float*)d_in[3];
    const float* W2  = (const float*)d_in[4];
    const float* b2  = (const float*)d_in[5];
    const float* Wh  = (const float*)d_in[6];
    const float* bh  = (const float*)d_in[7];
    const float* Wc1 = (const float*)d_in[8];
    const float* bc1 = (const float*)d_in[9];
    const float* Wc2 = (const float*)d_in[10];
    const float* bc2 = (const float*)d_in[11];
    const float* Wc3 = (const float*)d_in[12];
    const float* bc3 = (const float*)d_in[13];
    float* out = (float*)d_out;
    short* ws  = (short*)d_ws;
    short* hG  = ws + HG_S;
    unsigned char* evG = (unsigned char*)d_ws + EVG_B;

    hipLaunchKernelGGL(prep, dim3(32), dim3(256), 0, stream,
                       W1, b1, W2, Wh, Wc1, bc1, Wc2, Wc3, ws);
    hipLaunchKernelGGL(trunk1, dim3(256), dim3(512), 0, stream,
                       x, ws, hG, evG);
    hipLaunchKernelGGL(head2, dim3(512), dim3(512), 0, stream,
                       act, b2, bc2, bh, bc3, ws, hG, evG, out);
}